// Round 1
// baseline (119.518 us; speedup 1.0000x reference)
//
#include <hip/hip_runtime.h>
#include <hip/hip_fp16.h>

#define TAU 0.07f
#define MARGIN 0.2f
#define NSPEC 64
#define BB 8192
#define DD 256

// ---------------- ws layout (bytes) ----------------
// zeroed by k1 each call:
//   0      float scalars[8]  [0]=triSum [1]=infoSum [2]=n_valid [3]=n_valid_i [4]=done(uint)
//   1024   float lseRow[B]        [1024,  33792)
//   33792  float lseCol[B]        [33792, 66560)
//   66560  float Ts[64*256]       [66560, 132096)   (atomic-accumulated by k2)
//   132096 float T[256]           [132096,133120)   (written by k5 designated block)
// unzeroed (fully written by k1):
//   288    int   counts[64]
//   544    int   offsets[64]
//   133120 int   memberList[B]
#define WS_SCALARS   0
#define WS_COUNTS    288
#define WS_OFFSETS   544
#define WS_LSEROW    1024
#define WS_LSECOL    33792
#define WS_TS        66560
#define WS_T         132096
#define WS_MEMBER    133120
#define ZERO_F4      8256   // float4 count covering [1024, 133120)

typedef _Float16 half8 __attribute__((ext_vector_type(8)));
typedef float float4v __attribute__((ext_vector_type(4)));
typedef unsigned int uint4v __attribute__((ext_vector_type(4)));

__device__ __forceinline__ uint4v pack8(float4 a, float4 b) {
  half8 h;
  h[0] = (_Float16)a.x; h[1] = (_Float16)a.y; h[2] = (_Float16)a.z; h[3] = (_Float16)a.w;
  h[4] = (_Float16)b.x; h[5] = (_Float16)b.y; h[6] = (_Float16)b.z; h[7] = (_Float16)b.w;
  return __builtin_bit_cast(uint4v, h);
}

// ---- k1: ws zeroing + counts + scan + scatter + valid-counts, single block 1024 thr ----
__global__ void k1_all(const int* __restrict__ ids, int* counts_g, int* offsets_g,
                       int* memberList, float* scalars, float4v* zb) {
  __shared__ int cnt[NSPEC];
  __shared__ int off[NSPEC];
  int tid = threadIdx.x;
  // zero the atomic-accumulated region (replaces hipMemsetAsync dispatch)
  float4v z4 = {0.f, 0.f, 0.f, 0.f};
  for (int u = tid; u < ZERO_F4; u += 1024) zb[u] = z4;
  if (tid < 8) ((unsigned*)scalars)[tid] = 0u;
  if (tid < NSPEC) cnt[tid] = 0;
  __syncthreads();
  int myS[8], myP[8];
  #pragma unroll
  for (int r = 0; r < 8; ++r) {
    int i = r * 1024 + tid;
    int s = ids[i];
    myS[r] = s;
    myP[r] = atomicAdd(&cnt[s], 1);
  }
  __syncthreads();
  if (tid < NSPEC) {  // exactly wave 0
    int o = 0;
    for (int t = 0; t < NSPEC; ++t) o += (t < tid) ? cnt[t] : 0;
    off[tid] = o;
    offsets_g[tid] = o;
    int c = cnt[tid];
    counts_g[tid] = c;
    unsigned long long bv = __ballot(c >= 2);
    float nvi = (c >= 2 && c <= BB - 1) ? (float)c : 0.f;
    for (int o2 = 1; o2 < 64; o2 <<= 1) nvi += __shfl_xor(nvi, o2);
    if (tid == 0) {
      scalars[2] = (float)__popcll(bv);
      scalars[3] = nvi;
    }
  }
  __syncthreads();
  #pragma unroll
  for (int r = 0; r < 8; ++r) {
    int i = r * 1024 + tid;
    memberList[off[myS[r]] + myP[r]] = i;
  }
}

// ---- k2: per-species text sums Ts[s][d], 8 row-slices per species + atomic merge ----
__global__ void k2_ts(const float* __restrict__ tx, const int* __restrict__ counts,
                      const int* __restrict__ offsets, const int* __restrict__ memberList,
                      float* Ts) {
  int s = blockIdx.x, r = blockIdx.y;
  int m = counts[s], g0 = offsets[s];
  int k0 = (m * r) >> 3, k1 = (m * (r + 1)) >> 3;
  if (k0 >= k1) return;
  int d = threadIdx.x;
  float acc = 0.f;
  for (int k = k0; k < k1; ++k) acc += tx[memberList[g0 + k] * DD + d];
  atomicAdd(&Ts[s * DD + d], acc);
}

// ---- k5: per-species masked sum-of-exp via MFMA f16; block (0,3,1) also computes T ----
// Block tile: 64 rows x 128 cols; K=256 in 4 chunks of 64.
// LDS fragment-order: 16B unit (ksl, row, quad) = row's d[kc*64+ksl*32+quad*8 .. +8) as f16.
__global__ void k5_lse(const float* __restrict__ sp, const float* __restrict__ tx,
                       const int* __restrict__ counts, const int* __restrict__ offsets,
                       const int* __restrict__ memberList,
                       const float* __restrict__ Ts, float* T,
                       float* lseRow, float* lseCol) {
  // fold former k2b_t into one (otherwise mostly-idle) block of this launch:
  // T[d] = sum_s Ts[s][d]. Legal: k2 completed (stream order); T read only by k6.
  if (blockIdx.x == 0 && blockIdx.y == 3 && blockIdx.z == 1) {
    int d = threadIdx.x;
    float acc = 0.f;
    #pragma unroll
    for (int s = 0; s < NSPEC; ++s) acc += Ts[s * DD + d];
    T[d] = acc;
  }

  __shared__ uint4v lds5[1536];  // A: [0,512) = 2*64*4 units; B: [512,1536) = 2*128*4
  int s = blockIdx.x;
  int m = counts[s];
  int g0 = offsets[s];
  int tid = threadIdx.x;
  int lane = tid & 63, wv = tid >> 6;
  int quad = lane >> 4, cl = lane & 15;

  for (int rt = blockIdx.y; rt * 64 < m; rt += gridDim.y) {
    for (int ct = blockIdx.z; ct * 128 < m; ct += gridDim.z) {
      float4v acc[8];
      #pragma unroll
      for (int cf = 0; cf < 8; ++cf) acc[cf] = (float4v){0.f, 0.f, 0.f, 0.f};

      for (int kc = 0; kc < 4; ++kc) {
        __syncthreads();
        // stage 1536 units, 6 per thread
        #pragma unroll
        for (int p = 0; p < 6; ++p) {
          int u = p * 256 + tid;
          int isB = u >= 512;
          int v = isB ? (u - 512) : u;
          int row = v >> 3;            // A: 0..63 ; B: 0..127
          int sub = v & 7;
          int ksl = sub >> 2, q = sub & 3;
          int d0 = kc * 64 + ksl * 32 + q * 8;
          int idx = isB ? (ct * 128 + row) : (rt * 64 + row);
          uint4v val = (uint4v){0u, 0u, 0u, 0u};
          if (idx < m) {
            const float* src = (isB ? tx : sp) + memberList[g0 + idx] * DD + d0;
            float4 f0 = *reinterpret_cast<const float4*>(src);
            float4 f1 = *reinterpret_cast<const float4*>(src + 4);
            val = pack8(f0, f1);
          }
          int dst = isB ? (512 + (ksl * 128 + row) * 4 + q)
                        : ((ksl * 64 + row) * 4 + q);
          lds5[dst] = val;
        }
        __syncthreads();
        #pragma unroll
        for (int ksl = 0; ksl < 2; ++ksl) {
          half8 a = __builtin_bit_cast(half8, lds5[(ksl * 64 + wv * 16 + cl) * 4 + quad]);
          #pragma unroll
          for (int cf = 0; cf < 8; ++cf) {
            half8 b = __builtin_bit_cast(half8, lds5[512 + (ksl * 128 + cf * 16 + cl) * 4 + quad]);
            acc[cf] = __builtin_amdgcn_mfma_f32_16x16x32_f16(a, b, acc[cf], 0, 0, 0);
          }
        }
      }

      // epilogue: masked exp, row/col sums
      int riBase = rt * 64 + wv * 16 + quad * 4;  // + reg
      float rowAcc[4] = {0.f, 0.f, 0.f, 0.f};
      #pragma unroll
      for (int cf = 0; cf < 8; ++cf) {
        int ci = ct * 128 + cf * 16 + cl;
        bool cv = ci < m;
        float colAcc = 0.f;
        #pragma unroll
        for (int reg = 0; reg < 4; ++reg) {
          bool rv = (riBase + reg) < m;
          float e = (rv && cv) ? __expf(acc[cf][reg] * (1.f / TAU)) : 0.f;
          rowAcc[reg] += e;
          colAcc += e;
        }
        colAcc += __shfl_xor(colAcc, 16);
        colAcc += __shfl_xor(colAcc, 32);
        if (quad == 0 && cv) atomicAdd(&lseCol[g0 + ci], colAcc);
      }
      #pragma unroll
      for (int reg = 0; reg < 4; ++reg) {
        float v = rowAcc[reg];
        v += __shfl_xor(v, 1);
        v += __shfl_xor(v, 2);
        v += __shfl_xor(v, 4);
        v += __shfl_xor(v, 8);
        if (cl == 0 && (riBase + reg) < m) atomicAdd(&lseRow[g0 + riBase + reg], v);
      }
    }
  }
}

// ---- k6: fused k4+k6+k7: one wave per g does the 3 exact f32 dots + CE + triplet,
//      block reduce, one atomic pair per block, last block writes the final output ----
__global__ void k6_fused(const float* __restrict__ sp, const float* __restrict__ tx,
                         const int* __restrict__ ids, const int* __restrict__ counts,
                         const int* __restrict__ memberList,
                         const float* __restrict__ Ts, const float* __restrict__ T,
                         const float* __restrict__ lseRow, const float* __restrict__ lseCol,
                         float* scalars, float* out) {
  __shared__ float red[32];  // [0..15]=info per wave, [16..31]=tri per wave
  int tid = threadIdx.x;
  int gt = blockIdx.x * 1024 + tid;
  int g = gt >> 6, lane = gt & 63;
  int i = memberList[g];
  int s = ids[i];
  int m = counts[s];
  float4 a = *reinterpret_cast<const float4*>(sp + i * DD + lane * 4);
  float4 b = *reinterpret_cast<const float4*>(tx + i * DD + lane * 4);
  float4 c = *reinterpret_cast<const float4*>(Ts + s * DD + lane * 4);
  float4 tv = *reinterpret_cast<const float4*>(T + lane * 4);
  float dDiag = a.x * b.x + a.y * b.y + a.z * b.z + a.w * b.w;
  float dTs   = a.x * c.x + a.y * c.y + a.z * c.z + a.w * c.w;
  float dT    = a.x * tv.x + a.y * tv.y + a.z * tv.z + a.w * tv.w;
  #pragma unroll
  for (int o = 1; o < 64; o <<= 1) {
    dDiag += __shfl_xor(dDiag, o);
    dTs   += __shfl_xor(dTs, o);
    dT    += __shfl_xor(dT, o);
  }
  if (lane == 0) {
    float term = 0.f, tri = 0.f;
    if (m >= 2) {
      term = (__logf(lseRow[g]) + __logf(lseCol[g]) - 2.f * dDiag * (1.f / TAU)) /
             (2.f * (float)m);
      float posMean = (dTs - dDiag) / fmaxf((float)(m - 1), 1.f);
      float negMean = (dT - dTs) / fmaxf((float)(BB - m), 1.f);
      if (m <= BB - 1) tri = fmaxf(negMean - posMean + MARGIN, 0.f);
    }
    int wv = tid >> 6;
    red[wv] = term;
    red[16 + wv] = tri;
  }
  __syncthreads();
  if (tid == 0) {
    float infoS = 0.f, triS = 0.f;
    #pragma unroll
    for (int w = 0; w < 16; ++w) { infoS += red[w]; triS += red[16 + w]; }
    atomicAdd(&scalars[1], infoS);
    atomicAdd(&scalars[0], triS);
    __threadfence();
    unsigned prev = atomicAdd((unsigned*)&scalars[4], 1u);
    if (prev == gridDim.x - 1) {   // last block: fold former k7_final
      float fi = atomicAdd(&scalars[1], 0.f);  // coherent device-scope reads
      float ft = atomicAdd(&scalars[0], 0.f);
      float nv = scalars[2];   // plain k1 outputs: visible since kernel boundary
      float nvi = scalars[3];
      out[0] = fi / fmaxf(nv, 1.f) + ft / fmaxf(nvi, 1.f);
    }
  }
}

extern "C" void kernel_launch(void* const* d_in, const int* in_sizes, int n_in,
                              void* d_out, int out_size, void* d_ws, size_t ws_size,
                              hipStream_t stream) {
  const float* sp = (const float*)d_in[0];
  const float* tx = (const float*)d_in[1];
  const int* ids = (const int*)d_in[2];
  float* out = (float*)d_out;

  char* ws = (char*)d_ws;
  float* scalars = (float*)(ws + WS_SCALARS);
  int* counts = (int*)(ws + WS_COUNTS);
  int* offsets = (int*)(ws + WS_OFFSETS);
  float* lseRow = (float*)(ws + WS_LSEROW);
  float* lseCol = (float*)(ws + WS_LSECOL);
  float* Ts = (float*)(ws + WS_TS);
  float* T = (float*)(ws + WS_T);
  int* memberList = (int*)(ws + WS_MEMBER);

  k1_all<<<1, 1024, 0, stream>>>(ids, counts, offsets, memberList, scalars,
                                 (float4v*)(ws + WS_LSEROW));
  k2_ts<<<dim3(NSPEC, 8), 256, 0, stream>>>(tx, counts, offsets, memberList, Ts);
  k5_lse<<<dim3(NSPEC, 4, 2), 256, 0, stream>>>(sp, tx, counts, offsets, memberList,
                                                Ts, T, lseRow, lseCol);
  k6_fused<<<BB / 16, 1024, 0, stream>>>(sp, tx, ids, counts, memberList, Ts, T,
                                         lseRow, lseCol, scalars, out);
}